// Round 3
// baseline (43629.474 us; speedup 1.0000x reference)
//
#include <hip/hip_runtime.h>

// ---------------------------------------------------------------------------
// Speller (LAS decoder) on MI355X — round 3.
// Key change vs round 2: NO memory fences anywhere in the persistent kernel.
// Round 2's gbar release/acquire fences emitted buffer_wbl2/buffer_inv
// (XCD-wide L2 writeback/invalidate) per block per barrier (~900x), nuking
// the L2-cached weights/kv every phase. Now all cross-phase state (h0/h1/
// hid/ctx/ebuf/sbuf/embsel, ~200KB/step) moves through relaxed agent-scope
// atomics (sc1 = L2-bypass, coherent at L3); read-only weights/kv stay
// L2-resident for the whole 300-step loop. Barrier is one-hop: every block
// polls the packed 256-word arrival array. Visibility: compiler emits
// s_waitcnt vmcnt(0) before s_barrier, so all of a block's L3-bound stores
// have completed before its arrival store issues.
// ---------------------------------------------------------------------------

typedef __attribute__((ext_vector_type(8))) short s8bf;   // 8 bf16 (4 VGPRs)
typedef __attribute__((ext_vector_type(4))) float f32x4;

#define SCALE_E 0.044194173824159216f   // 1/sqrt(512)

struct Ptrs {
  const float* enc; const int* elen; const int* y;
  const float* emb;
  const float* Wih0; const float* Whh0; const float* bih0; const float* bhh0;
  const float* Wih1; const float* Whh1; const float* bih1; const float* bhh1;
  const float* Wq; const float* Wk; const float* Wv;
  const float* Wout; const float* bout; const float* bchar;
  unsigned short* kv;     // [64000][1024] bf16: [0,512) keys2 (Wq folded), [512,1024) vals
  unsigned short* W0p;    // [2048][1536] bf16, gate-permuted rows
  unsigned short* W1p;    // [2048][1024] bf16, gate-permuted
  unsigned short* Wob;    // [512][1024] bf16
  unsigned short* WkvT;   // [1024][512] bf16
  unsigned short* embbf;  // [31][512] bf16
  float* b0p; float* b1p; // [2048] permuted summed biases
  unsigned short* h0b;    // [2][64][512] bf16 (parity t&1) — coherent
  unsigned short* h1b;    // [2][64][512] bf16 — coherent
  unsigned short* hidb;   // [64][512] bf16 — coherent
  unsigned short* embsel; // [64][512] bf16 — coherent
  float* c0s; float* c1s; // [64][512] fp32 cell states (block-private)
  float* ctxa;            // [2][64][512] unnormalized ctx accumulator — coherent
  float* ebuf;            // [2][64][1024] unnormalized exp(e) — coherent
  float* sbuf;            // [2][64] softmax denominators — coherent
  int* barArr;            // [256] packed arrival epochs
  float* out;             // d_out: [64][300][31] logits then [64][300][1000] attn
};

__device__ __forceinline__ unsigned short f2bf(float f) {
  unsigned u = __float_as_uint(f);
  u += 0x7fffu + ((u >> 16) & 1u);          // RNE
  return (unsigned short)(u >> 16);
}
__device__ __forceinline__ float bf2f(unsigned short h) {
  return __uint_as_float(((unsigned)h) << 16);
}
__device__ __forceinline__ float sigm(float x) { return 1.f / (1.f + __expf(-x)); }

// --- coherent (L2-bypassing, agent-scope, relaxed) access helpers ----------
__device__ __forceinline__ unsigned long long ald64(const void* p) {
  return __hip_atomic_load((unsigned long long*)p, __ATOMIC_RELAXED,
                           __HIP_MEMORY_SCOPE_AGENT);
}
__device__ __forceinline__ void ast64(void* p, unsigned long long v) {
  __hip_atomic_store((unsigned long long*)p, v, __ATOMIC_RELAXED,
                     __HIP_MEMORY_SCOPE_AGENT);
}
__device__ __forceinline__ void ast32(void* p, unsigned v) {
  __hip_atomic_store((unsigned*)p, v, __ATOMIC_RELAXED, __HIP_MEMORY_SCOPE_AGENT);
}
__device__ __forceinline__ float aldf(const float* p) {
  return __hip_atomic_load((float*)p, __ATOMIC_RELAXED, __HIP_MEMORY_SCOPE_AGENT);
}
__device__ __forceinline__ void astf(float* p, float v) {
  __hip_atomic_store(p, v, __ATOMIC_RELAXED, __HIP_MEMORY_SCOPE_AGENT);
}
__device__ __forceinline__ void ast16(unsigned short* p, unsigned short v) {
  __hip_atomic_store(p, v, __ATOMIC_RELAXED, __HIP_MEMORY_SCOPE_AGENT);
}
__device__ __forceinline__ s8bf ald_frag(const unsigned short* p) {
  union { unsigned long long u[2]; s8bf v; } x;
  x.u[0] = ald64(p); x.u[1] = ald64(p + 4);
  return x.v;
}
__device__ __forceinline__ void ald_f8(const float* p, float* d) {
  union { unsigned long long u; float f[2]; } a, b, c, e;
  a.u = ald64(p); b.u = ald64(p + 2); c.u = ald64(p + 4); e.u = ald64(p + 6);
  d[0] = a.f[0]; d[1] = a.f[1]; d[2] = b.f[0]; d[3] = b.f[1];
  d[4] = c.f[0]; d[5] = c.f[1]; d[6] = e.f[0]; d[7] = e.f[1];
}

// ---------------------------------------------------------------------------
// One-hop fence-free grid barrier: arrival store (atomic, L3), then every
// block's wave 0 polls the whole packed array (2 u64 loads/lane).
// __syncthreads() drains each wave's vmcnt before the arrival store.
// ---------------------------------------------------------------------------
__device__ __forceinline__ void gbar(const Ptrs& P, int epoch) {
  __syncthreads();
  int tid = threadIdx.x;
  if (tid == 0)
    __hip_atomic_store(P.barArr + blockIdx.x, epoch, __ATOMIC_RELAXED,
                       __HIP_MEMORY_SCOPE_AGENT);
  if (tid < 64) {
    const unsigned long long* base = (const unsigned long long*)P.barArr;
    for (;;) {
      unsigned long long v0 = ald64(base + tid);
      unsigned long long v1 = ald64(base + 64 + tid);
      int ok = ((int)(v0 & 0xffffffffu) >= epoch) && ((int)(v0 >> 32) >= epoch) &&
               ((int)(v1 & 0xffffffffu) >= epoch) && ((int)(v1 >> 32) >= epoch);
      if (__all(ok)) break;
      __builtin_amdgcn_s_sleep(1);
    }
  }
  __syncthreads();
  asm volatile("" ::: "memory");
}

// ---------------------------------------------------------------------------
__global__ void k_init(Ptrs P) {
  int g = blockIdx.x * 256 + threadIdx.x;            // 65536 threads
  if (g < 256) P.barArr[g] = 0;
  for (int i = g; i < 32768; i += 65536) { P.c0s[i] = 0.f; P.c1s[i] = 0.f; }
  for (int i = g; i < 65536; i += 65536) {
    P.h0b[i] = 0; P.h1b[i] = 0; P.ctxa[i] = 0.f;
  }
  for (int i = g; i < 131072; i += 65536) P.ebuf[i] = 0.f;
  if (g < 128) P.sbuf[g] = 0.f;
}

// ---------------------------------------------------------------------------
// k_prep: bf16 weight conversion + gate permutation + Wk@Wq^T fold
// ---------------------------------------------------------------------------
__global__ void k_prep(Ptrs P) {
  int bid = blockIdx.x, tid = threadIdx.x;
  for (int ri = 0; ri < 8; ++ri) {
    int gp = bid * 8 + ri;
    int r = (gp & 3) * 512 + (gp >> 2);
    for (int k = tid; k < 1536; k += 256)
      P.W0p[(size_t)gp * 1536 + k] =
          f2bf(k < 1024 ? P.Wih0[(size_t)r * 1024 + k] : P.Whh0[(size_t)r * 512 + (k - 1024)]);
    for (int k = tid; k < 1024; k += 256)
      P.W1p[(size_t)gp * 1024 + k] =
          f2bf(k < 512 ? P.Wih1[(size_t)r * 512 + k] : P.Whh1[(size_t)r * 512 + (k - 512)]);
    if (tid == 0) {
      P.b0p[gp] = P.bih0[r] + P.bhh0[r];
      P.b1p[gp] = P.bih1[r] + P.bhh1[r];
    }
  }
  for (int ri = 0; ri < 2; ++ri) {
    int n = bid * 2 + ri;
    for (int k = tid; k < 1024; k += 256)
      P.Wob[(size_t)n * 1024 + k] = f2bf(P.Wout[(size_t)n * 1024 + k]);
  }
  {
    int g = bid * 256 + tid;
    if (g < 31 * 512) P.embbf[g] = f2bf(P.emb[g]);
  }
  for (int ri = 0; ri < 4; ++ri) {
    int n = bid * 4 + ri;
    if (n < 512) {
      const float* wq = P.Wq + (size_t)n * 512;
      for (int k = tid; k < 512; k += 256) {
        const float* wk = P.Wk + (size_t)k * 512;
        float s0 = 0.f, s1 = 0.f, s2 = 0.f, s3 = 0.f;
        for (int j = 0; j < 512; j += 4) {
          f32x4 a = *(const f32x4*)(wk + j);
          f32x4 b = *(const f32x4*)(wq + j);
          s0 = fmaf(a[0], b[0], s0); s1 = fmaf(a[1], b[1], s1);
          s2 = fmaf(a[2], b[2], s2); s3 = fmaf(a[3], b[3], s3);
        }
        P.WkvT[(size_t)n * 512 + k] = f2bf((s0 + s1) + (s2 + s3));
      }
    } else {
      for (int k = tid; k < 512; k += 256)
        P.WkvT[(size_t)n * 512 + k] = f2bf(P.Wv[(size_t)k * 512 + (n - 512)]);
    }
  }
}

// ---------------------------------------------------------------------------
// k_kv: kv[m][n] = enc[m][:] @ WkvT[n][:]  (M=64000, N=1024, K=512)
// ---------------------------------------------------------------------------
__global__ __launch_bounds__(1024) void k_kv(Ptrs P) {
  int bid = blockIdx.x, tid = threadIdx.x;
  int w = tid >> 6, ln = tid & 63;
  __shared__ unsigned short lds2[16][16][16];
  int mt = bid * 16 + w;
  bool valid = mt < 4000;
  s8bf afr[16];
  if (valid) {
    const float* ar = P.enc + (size_t)(mt * 16 + (ln & 15)) * 512 + ((ln >> 4) * 8);
    for (int ks = 0; ks < 16; ++ks) {
      f32x4 v0 = *(const f32x4*)(ar + ks * 32);
      f32x4 v1 = *(const f32x4*)(ar + ks * 32 + 4);
      s8bf a;
      a[0] = (short)f2bf(v0[0]); a[1] = (short)f2bf(v0[1]);
      a[2] = (short)f2bf(v0[2]); a[3] = (short)f2bf(v0[3]);
      a[4] = (short)f2bf(v1[0]); a[5] = (short)f2bf(v1[1]);
      a[6] = (short)f2bf(v1[2]); a[7] = (short)f2bf(v1[3]);
      afr[ks] = a;
    }
  }
  for (int nt = 0; nt < 64; ++nt) {
    if (valid) {
      f32x4 acc = {0.f, 0.f, 0.f, 0.f};
      const unsigned short* br = P.WkvT + (size_t)(nt * 16 + (ln & 15)) * 512 + ((ln >> 4) * 8);
      for (int ks = 0; ks < 16; ++ks) {
        s8bf b = *(const s8bf*)(br + ks * 32);
        acc = __builtin_amdgcn_mfma_f32_16x16x32_bf16(afr[ks], b, acc, 0, 0, 0);
      }
      for (int r = 0; r < 4; ++r)
        lds2[w][(ln >> 4) * 4 + r][ln & 15] = f2bf(acc[r]);
    }
    __syncthreads();
    if (valid && ln < 32) {
      int row = ln >> 1, half = ln & 1;
      s8bf v = *(const s8bf*)&lds2[w][row][half * 8];
      *(s8bf*)(P.kv + (size_t)(mt * 16 + row) * 1024 + nt * 16 + half * 8) = v;
    }
    __syncthreads();
  }
}

// ---------------------------------------------------------------------------
// LSTM0: gates = [emb|ctx(t-1)|h0(t-1)] @ W0p^T; blocks 0..31
// ---------------------------------------------------------------------------
__device__ __forceinline__ void lstm0_phase(int bid, int tid, int t, const Ptrs& P,
                                            float (*lds_g)[16][16]) {
  int w = tid >> 6, ln = tid & 63;
  int mt = w & 3, nt = bid * 4 + (w >> 2);
  int brow = mt * 16 + (ln & 15), koff = (ln >> 4) * 8;
  int cur = t & 1, prv = cur ^ 1;
  const unsigned short* bp = P.W0p + (size_t)(nt * 16 + (ln & 15)) * 1536 + koff;
  f32x4 acc = {0.f, 0.f, 0.f, 0.f};
  if (t == 299) {
    const unsigned short* er = P.embsel + (size_t)brow * 512 + koff;
    for (int ks = 0; ks < 16; ++ks) {
      s8bf af = ald_frag(er + ks * 32);
      s8bf bf8 = *(const s8bf*)(bp + ks * 32);
      acc = __builtin_amdgcn_mfma_f32_16x16x32_bf16(af, bf8, acc, 0, 0, 0);
    }
  } else {
    int sym = (t == 0) ? 0 : P.y[brow * 300 + t];
    const unsigned short* er = P.embbf + (size_t)sym * 512 + koff;
    for (int ks = 0; ks < 16; ++ks) {
      s8bf af = *(const s8bf*)(er + ks * 32);     // constant, cached
      s8bf bf8 = *(const s8bf*)(bp + ks * 32);
      acc = __builtin_amdgcn_mfma_f32_16x16x32_bf16(af, bf8, acc, 0, 0, 0);
    }
  }
  if (t > 0) {
    float inv = 1.f / aldf(P.sbuf + prv * 64 + brow);
    const float* cp = P.ctxa + prv * 32768 + (size_t)brow * 512 + koff;
    for (int ks = 0; ks < 16; ++ks) {
      float v[8];
      ald_f8(cp + ks * 32, v);
      s8bf af;
      for (int j = 0; j < 8; ++j) af[j] = (short)f2bf(v[j] * inv);
      s8bf bf8 = *(const s8bf*)(bp + 512 + ks * 32);
      acc = __builtin_amdgcn_mfma_f32_16x16x32_bf16(af, bf8, acc, 0, 0, 0);
    }
  }
  const unsigned short* hp = P.h0b + prv * 32768 + (size_t)brow * 512 + koff;
  for (int ks = 0; ks < 16; ++ks) {
    s8bf af = ald_frag(hp + ks * 32);
    s8bf bf8 = *(const s8bf*)(bp + 1024 + ks * 32);
    acc = __builtin_amdgcn_mfma_f32_16x16x32_bf16(af, bf8, acc, 0, 0, 0);
  }
  float bias = P.b0p[nt * 16 + (ln & 15)];
  for (int r = 0; r < 4; ++r)
    lds_g[w][(ln >> 4) * 4 + r][ln & 15] = acc[r] + bias;
  __syncthreads();
  int rb = ln >> 2, c = ln & 3;
  float gi = lds_g[w][rb][4 * c + 0];
  float gf = lds_g[w][rb][4 * c + 1];
  float gg = lds_g[w][rb][4 * c + 2];
  float go = lds_g[w][rb][4 * c + 3];
  int bb = mt * 16 + rb, d = nt * 4 + c;
  float co = P.c0s[bb * 512 + d];
  float cn = fmaf(sigm(gf), co, sigm(gi) * tanhf(gg));
  float h = sigm(go) * tanhf(cn);
  P.c0s[bb * 512 + d] = cn;
  ast16(P.h0b + cur * 32768 + bb * 512 + d, f2bf(h));
}

// ---------------------------------------------------------------------------
// LSTM1: gates = [h0(t)|h1(t-1)] @ W1p^T; blocks 0..31
// ---------------------------------------------------------------------------
__device__ __forceinline__ void lstm1_phase(int bid, int tid, int t, const Ptrs& P,
                                            float (*lds_g)[16][16]) {
  int w = tid >> 6, ln = tid & 63;
  int mt = w & 3, nt = bid * 4 + (w >> 2);
  int brow = mt * 16 + (ln & 15), koff = (ln >> 4) * 8;
  int cur = t & 1, prv = cur ^ 1;
  const unsigned short* bp = P.W1p + (size_t)(nt * 16 + (ln & 15)) * 1024 + koff;
  const unsigned short* h0p = P.h0b + cur * 32768 + (size_t)brow * 512 + koff;
  const unsigned short* h1p = P.h1b + prv * 32768 + (size_t)brow * 512 + koff;
  f32x4 acc = {0.f, 0.f, 0.f, 0.f};
  for (int ks = 0; ks < 16; ++ks) {
    s8bf af = ald_frag(h0p + ks * 32);
    s8bf bf8 = *(const s8bf*)(bp + ks * 32);
    acc = __builtin_amdgcn_mfma_f32_16x16x32_bf16(af, bf8, acc, 0, 0, 0);
  }
  for (int ks = 0; ks < 16; ++ks) {
    s8bf af = ald_frag(h1p + ks * 32);
    s8bf bf8 = *(const s8bf*)(bp + 512 + ks * 32);
    acc = __builtin_amdgcn_mfma_f32_16x16x32_bf16(af, bf8, acc, 0, 0, 0);
  }
  float bias = P.b1p[nt * 16 + (ln & 15)];
  for (int r = 0; r < 4; ++r)
    lds_g[w][(ln >> 4) * 4 + r][ln & 15] = acc[r] + bias;
  __syncthreads();
  int rb = ln >> 2, c = ln & 3;
  float gi = lds_g[w][rb][4 * c + 0];
  float gf = lds_g[w][rb][4 * c + 1];
  float gg = lds_g[w][rb][4 * c + 2];
  float go = lds_g[w][rb][4 * c + 3];
  int bb = mt * 16 + rb, d = nt * 4 + c;
  float co = P.c1s[bb * 512 + d];
  float cn = fmaf(sigm(gf), co, sigm(gi) * tanhf(gg));
  float h = sigm(go) * tanhf(cn);
  P.c1s[bb * 512 + d] = cn;
  ast16(P.h1b + cur * 32768 + bb * 512 + d, f2bf(h));
}

// ---------------------------------------------------------------------------
// hid(s) = relu([h1(s)|ctx(s)] @ Wout^T + bout); blocks 32..47
// ---------------------------------------------------------------------------
__device__ __forceinline__ void hid_phase(int bid, int tid, int s, const Ptrs& P,
                                          float (*lds_g)[16][16]) {
  int w = tid >> 6, ln = tid & 63;
  int nl = w >> 3, kq = (w >> 2) & 1, mt = w & 3;
  int nt = (bid - 32) * 2 + nl;
  int brow = mt * 16 + (ln & 15), koff = (ln >> 4) * 8;
  int par = s & 1;
  const unsigned short* bp = P.Wob + (size_t)(nt * 16 + (ln & 15)) * 1024 + kq * 512 + koff;
  f32x4 acc = {0.f, 0.f, 0.f, 0.f};
  if (kq == 0) {
    const unsigned short* ap = P.h1b + par * 32768 + (size_t)brow * 512 + koff;
    for (int ks = 0; ks < 16; ++ks) {
      s8bf af = ald_frag(ap + ks * 32);
      s8bf bf8 = *(const s8bf*)(bp + ks * 32);
      acc = __builtin_amdgcn_mfma_f32_16x16x32_bf16(af, bf8, acc, 0, 0, 0);
    }
  } else {
    float inv = 1.f / aldf(P.sbuf + par * 64 + brow);
    const float* ap = P.ctxa + par * 32768 + (size_t)brow * 512 + koff;
    for (int ks = 0; ks < 16; ++ks) {
      float v[8];
      ald_f8(ap + ks * 32, v);
      s8bf af;
      for (int j = 0; j < 8; ++j) af[j] = (short)f2bf(v[j] * inv);
      s8bf bf8 = *(const s8bf*)(bp + ks * 32);
      acc = __builtin_amdgcn_mfma_f32_16x16x32_bf16(af, bf8, acc, 0, 0, 0);
    }
  }
  for (int r = 0; r < 4; ++r)
    lds_g[w][(ln >> 4) * 4 + r][ln & 15] = acc[r];
  __syncthreads();
  // 2048 bf16 outputs -> 1024 packed u32 coherent stores (one per thread)
  int row = tid >> 4;                  // 0..63
  int cl = (tid & 15) * 2;             // 0..30
  int nl2 = cl >> 4, mt2 = row >> 4, rb = row & 15;
  int cc0 = cl & 15, cc1 = cc0 + 1;
  int ntg = (bid - 32) * 2 + nl2;
  float a0 = lds_g[nl2 * 8 + mt2][rb][cc0] + lds_g[nl2 * 8 + 4 + mt2][rb][cc0];
  float a1 = lds_g[nl2 * 8 + mt2][rb][cc1] + lds_g[nl2 * 8 + 4 + mt2][rb][cc1];
  a0 = fmaxf(a0 + P.bout[ntg * 16 + cc0], 0.f);
  a1 = fmaxf(a1 + P.bout[ntg * 16 + cc1], 0.f);
  unsigned u = (unsigned)f2bf(a0) | ((unsigned)f2bf(a1) << 16);
  ast32(P.hidb + (size_t)row * 512 + (bid - 32) * 32 + cl, u);
}

// ---------------------------------------------------------------------------
// logits(s) from hidb; blocks 32..39, waves 0..7 (one b per wave)
// ---------------------------------------------------------------------------
__device__ __forceinline__ void logits_phase(int bid, int tid, int s, const Ptrs& P,
                                             bool do_argmax) {
  int w = tid >> 6, ln = tid & 63;
  if (w >= 8) return;
  int b = (bid - 32) * 8 + w;
  float hv[8];
  s8bf hh = ald_frag(P.hidb + (size_t)b * 512 + ln * 8);
  for (int j = 0; j < 8; ++j) hv[j] = bf2f((unsigned short)hh[j]);
  float mx = -3.4e38f; int am = 0;
  for (int v = 0; v < 31; ++v) {
    s8bf ee = *(const s8bf*)(P.embbf + (size_t)v * 512 + ln * 8);
    float p = 0.f;
    for (int j = 0; j < 8; ++j) p = fmaf(bf2f((unsigned short)ee[j]), hv[j], p);
    for (int off = 32; off; off >>= 1) p += __shfl_down(p, off);
    if (ln == 0) {
      float lg = p + P.bchar[v];
      P.out[(size_t)b * 9300 + (size_t)s * 31 + v] = lg;
      if (lg > mx) { mx = lg; am = v; }
    }
  }
  if (do_argmax) {
    am = __shfl(am, 0);
    union { s8bf v; unsigned long long u[2]; } x;
    x.v = *(const s8bf*)(P.embbf + (size_t)am * 512 + ln * 8);
    unsigned short* dst = P.embsel + (size_t)b * 512 + ln * 8;
    ast64(dst, x.u[0]); ast64(dst + 4, x.u[1]);
  }
}

// attention-plot normalize+write for step s; blocks 48..63
__device__ __forceinline__ void attnnorm_phase(int bid, int tid, int s, const Ptrs& P) {
  int idx = (bid - 48) * 1024 + tid;
  if (idx >= 16000) return;
  int b = idx / 250, r = idx - b * 250;
  int par = s & 1;
  float inv = 1.f / aldf(P.sbuf + par * 64 + b);
  const float* e = P.ebuf + par * 65536 + b * 1024 + r * 4;
  f32x4 v;
  v[0] = aldf(e + 0) * inv; v[1] = aldf(e + 1) * inv;
  v[2] = aldf(e + 2) * inv; v[3] = aldf(e + 3) * inv;
  *(f32x4*)(P.out + 595200 + (size_t)b * 300000 + (size_t)s * 1000 + r * 4) = v;
}

// zero ctxa/sbuf parity t for the upcoming sweep; blocks 40..47
__device__ __forceinline__ void zero_phase(int bid, int tid, int t, const Ptrs& P) {
  int idx = (bid - 40) * 1024 + tid;                 // 0..8191, 4 floats each
  float* dst = P.ctxa + (t & 1) * 32768 + idx * 4;
  ast64(dst, 0ull); ast64(dst + 2, 0ull);
  if (bid == 40 && tid < 64) astf(P.sbuf + (t & 1) * 64 + tid, 0.f);
}

// fused attention sweep over kv; all 256 blocks
__device__ __forceinline__ void sweep(int bid, int tid, int t, const Ptrs& P,
                                      float (*lds_ctx)[512], float* lds_s) {
  int w = tid >> 6, ln = tid & 63;
  int b = bid >> 2, ch = bid & 3;
  int par = t & 1;
  int len = P.elen[b];
  int t0 = ch * 250;
  int lim = t0 + 250; if (len < lim) lim = len;
  float h1r[8];
  {
    s8bf hh = ald_frag(P.h1b + par * 32768 + (size_t)b * 512 + ln * 8);
    for (int j = 0; j < 8; ++j) h1r[j] = bf2f((unsigned short)hh[j]);
  }
  float acc[8] = {0.f, 0.f, 0.f, 0.f, 0.f, 0.f, 0.f, 0.f};
  float wsum = 0.f;
  float* eb = P.ebuf + par * 65536 + b * 1024;
  const unsigned short* kvb = P.kv + (size_t)b * 1000 * 1024;   // cached (no inv!)
  int tt = t0 + w;
  bool have = tt < lim;
  s8bf kk, vv;
  if (have) {
    const unsigned short* row = kvb + (size_t)tt * 1024 + ln * 8;
    kk = *(const s8bf*)(row);
    vv = *(const s8bf*)(row + 512);
  }
  while (have) {
    int ttn = tt + 16;
    bool haven = ttn < lim;
    s8bf kk2, vv2;
    if (haven) {
      const unsigned short* row = kvb + (size_t)ttn * 1024 + ln * 8;
      kk2 = *(const s8bf*)(row);
      vv2 = *(const s8bf*)(row + 512);
    }
    float p0 = 0.f, p1 = 0.f;
    for (int j = 0; j < 8; j += 2) {
      p0 = fmaf(bf2f((unsigned short)kk[j]), h1r[j], p0);
      p1 = fmaf(bf2f((unsigned short)kk[j + 1]), h1r[j + 1], p1);
    }
    float p = p0 + p1;
    p += __shfl_xor(p, 32); p += __shfl_xor(p, 16); p += __shfl_xor(p, 8);
    p += __shfl_xor(p, 4);  p += __shfl_xor(p, 2);  p += __shfl_xor(p, 1);
    float pe = __expf(p * SCALE_E);
    if (ln == 0) { astf(eb + tt, pe); wsum += pe; }
    for (int j = 0; j < 8; ++j)
      acc[j] = fmaf(bf2f((unsigned short)vv[j]), pe, acc[j]);
    kk = kk2; vv = vv2; tt = ttn; have = haven;
  }
  if (ln == 0) lds_s[w] = wsum;
  for (int j = 0; j < 8; ++j) lds_ctx[w][ln * 8 + j] = acc[j];
  __syncthreads();
  if (tid < 512) {
    float s = 0.f;
    for (int i = 0; i < 16; ++i) s += lds_ctx[i][tid];
    unsafeAtomicAdd(P.ctxa + par * 32768 + b * 512 + tid, s);   // device-scope, L3
  }
  if (tid == 0) {
    float s = 0.f;
    for (int i = 0; i < 16; ++i) s += lds_s[i];
    unsafeAtomicAdd(P.sbuf + par * 64 + b, s);
  }
}

// ---------------------------------------------------------------------------
// k_main: persistent decode loop, 3 fence-free grid barriers / step
// ---------------------------------------------------------------------------
__global__ __launch_bounds__(1024) void k_main(Ptrs P) {
  __shared__ float lds_g[16][16][16];
  __shared__ float lds_ctx[16][512];
  __shared__ float lds_s[16];
  int bid = blockIdx.x, tid = threadIdx.x;
  int ep = 0;

  for (int t = 0; t < 300; ++t) {
    // -- Phase A: LSTM0(t) | hid(t-1) | attn-norm(t-1) ----------------------
    if (bid < 32) lstm0_phase(bid, tid, t, P, lds_g);
    else if (bid < 48) { if (t > 0) hid_phase(bid, tid, t - 1, P, lds_g); }
    else if (bid < 64) { if (t > 0) attnnorm_phase(bid, tid, t - 1, P); }
    gbar(P, ++ep);

    // -- Phase B: LSTM1(t) | logits(t-1) | zero ctxa/sbuf parity t ----------
    if (bid < 32) lstm1_phase(bid, tid, t, P, lds_g);
    else if (bid < 40) { if (t > 0) logits_phase(bid, tid, t - 1, P, false); }
    else if (bid < 48) zero_phase(bid, tid, t, P);
    gbar(P, ++ep);

    // -- Phase C: fused attention sweep -------------------------------------
    sweep(bid, tid, t, P, lds_ctx, lds_s);
    gbar(P, ++ep);

    // -- step 298: need argmax(logits_298) as step-299 input ----------------
    if (t == 298) {
      if (bid >= 32 && bid < 48) hid_phase(bid, tid, 298, P, lds_g);
      gbar(P, ++ep);
      if (bid >= 32 && bid < 40) logits_phase(bid, tid, 298, P, true);
      gbar(P, ++ep);
    }
  }
  // tail: hid(299) + attn(299), then logits(299)
  if (bid >= 32 && bid < 48) hid_phase(bid, tid, 299, P, lds_g);
  else if (bid >= 48 && bid < 64) attnnorm_phase(bid, tid, 299, P);
  gbar(P, ++ep);
  if (bid >= 32 && bid < 40) logits_phase(bid, tid, 299, P, false);
}

// ---------------------------------------------------------------------------
extern "C" void kernel_launch(void* const* d_in, const int* in_sizes, int n_in,
                              void* d_out, int out_size, void* d_ws, size_t ws_size,
                              hipStream_t stream) {
  (void)in_sizes; (void)n_in; (void)out_size; (void)ws_size;
  Ptrs P;
  P.enc   = (const float*)d_in[0];
  P.elen  = (const int*)d_in[1];
  P.y     = (const int*)d_in[2];
  P.emb   = (const float*)d_in[3];
  P.Wih0  = (const float*)d_in[4];
  P.Whh0  = (const float*)d_in[5];
  P.bih0  = (const float*)d_in[6];
  P.bhh0  = (const float*)d_in[7];
  P.Wih1  = (const float*)d_in[8];
  P.Whh1  = (const float*)d_in[9];
  P.bih1  = (const float*)d_in[10];
  P.bhh1  = (const float*)d_in[11];
  P.Wq    = (const float*)d_in[12];
  P.Wk    = (const float*)d_in[13];
  P.Wv    = (const float*)d_in[14];
  P.Wout  = (const float*)d_in[15];
  P.bout  = (const float*)d_in[16];
  P.bchar = (const float*)d_in[17];
  P.out   = (float*)d_out;

  char* ws = (char*)d_ws;
  size_t o = 0;
  auto alloc = [&](size_t n) { char* p = ws + o; o = (o + n + 255) & ~(size_t)255; return p; };
  P.kv     = (unsigned short*)alloc(64000ull * 1024 * 2);   // 131 MB
  P.W0p    = (unsigned short*)alloc(2048ull * 1536 * 2);
  P.W1p    = (unsigned short*)alloc(2048ull * 1024 * 2);
  P.Wob    = (unsigned short*)alloc(512ull * 1024 * 2);
  P.WkvT   = (unsigned short*)alloc(1024ull * 512 * 2);
  P.embbf  = (unsigned short*)alloc(31ull * 512 * 2);
  P.b0p    = (float*)alloc(2048 * 4);
  P.b1p    = (float*)alloc(2048 * 4);
  P.h0b    = (unsigned short*)alloc(2ull * 64 * 512 * 2);
  P.h1b    = (unsigned short*)alloc(2ull * 64 * 512 * 2);
  P.hidb   = (unsigned short*)alloc(64ull * 512 * 2);
  P.embsel = (unsigned short*)alloc(64ull * 512 * 2);
  P.c0s    = (float*)alloc(64ull * 512 * 4);
  P.c1s    = (float*)alloc(64ull * 512 * 4);
  P.ctxa   = (float*)alloc(2ull * 64 * 512 * 4);
  P.ebuf   = (float*)alloc(2ull * 64 * 1024 * 4);
  P.sbuf   = (float*)alloc(2ull * 64 * 4);
  P.barArr = (int*)alloc(256 * 4);

  k_init<<<dim3(256), dim3(256), 0, stream>>>(P);
  k_prep<<<dim3(256), dim3(256), 0, stream>>>(P);
  k_kv<<<dim3(256), dim3(1024), 0, stream>>>(P);
  k_main<<<dim3(256), dim3(1024), 0, stream>>>(P);
}